// Round 4
// baseline (219.368 us; speedup 1.0000x reference)
//
#include <hip/hip_runtime.h>

typedef short short8 __attribute__((ext_vector_type(8)));
typedef float f32x4 __attribute__((ext_vector_type(4)));
typedef unsigned short u16;
typedef unsigned int u32;

#define E_EDGES 100000
#define NNODES  50000

// ---- workspace layout (float offsets) ----
#define WS_ATPK 0        // At-extended bf16 packed [h/8][272][h%8] : 34816 u16 = 17408 f
#define WS_WFPK 17408    // Wf bf16 packed [c/8][128][c%8]          : 32768 u16 = 16384 f
#define WS_EXA0 33792    // extended bias [272] fp32 (a0 | cg | c0+pb-bias | 0)
#define WS_BF   34064    // bf [128]
#define WS_VOG  34192    // Vo_g [4][128] fp32
#define WS_PART 34704    // pooled partials [256][512]
#define WS_GF16 165888   // bf16 copy of global_feats: 50000*512 u16 = 12.8M floats
#define WS_FLOATS_GF16 (WS_GF16 + (NNODES * 512 / 2))

#define POOL_BLOCKS 256
#define POOL_ROWS   196
#define PREP_ITEMS  67468
#define PREP_BLOCKS 264   // ceil(PREP_ITEMS/256)

#define OUT_POOL ((size_t)E_EDGES * 384)
#define OUT_GAW  (OUT_POOL + 512)

static constexpr float SCALE = 0.08838834764831845f; // 1/sqrt(128)

__device__ __forceinline__ u16 f2bf(float x) {            // RNE fp32->bf16
    u32 u = __float_as_uint(x);
    u += 0x7fffu + ((u >> 16) & 1u);
    return (u16)(u >> 16);
}
__device__ __forceinline__ float blo(u32 u) { return __uint_as_float(u << 16); }
__device__ __forceinline__ float bhi(u32 u) { return __uint_as_float(u & 0xffff0000u); }

// ---------- fused: pooled partials (+ gf->bf16 copy)  |  local-weight prep ----------
__global__ void k_pre(const float* __restrict__ gf,
                      const float* __restrict__ wq_l, const float* __restrict__ wk_l,
                      const float* __restrict__ wv_l, const float* __restrict__ bq_l,
                      const float* __restrict__ bk_l, const float* __restrict__ bv_l,
                      const float* __restrict__ wo_l, const float* __restrict__ bo_l,
                      u16* __restrict__ gf16, float* __restrict__ ws) {
    __shared__ float4 sh[128];
    int t = threadIdx.x;
    if (blockIdx.x < POOL_BLOCKS) {
        float* part = ws + WS_PART;
        int b = blockIdx.x;
        int c4 = (t & 127) * 4, half = t >> 7;
        int n0 = b * POOL_ROWS, n1 = min(NNODES, n0 + POOL_ROWS);
        float4 acc = {0.f, 0.f, 0.f, 0.f};
        if (gf16) {
            for (int n = n0 + half; n < n1; n += 2) {
                float4 v = *(const float4*)(gf + (size_t)n * 512 + c4);
                acc.x += v.x; acc.y += v.y; acc.z += v.z; acc.w += v.w;
                uint2 pk;
                pk.x = (u32)f2bf(v.x) | ((u32)f2bf(v.y) << 16);
                pk.y = (u32)f2bf(v.z) | ((u32)f2bf(v.w) << 16);
                *(uint2*)(gf16 + (size_t)n * 512 + c4) = pk;
            }
        } else {
            for (int n = n0 + half; n < n1; n += 2) {
                float4 v = *(const float4*)(gf + (size_t)n * 512 + c4);
                acc.x += v.x; acc.y += v.y; acc.z += v.z; acc.w += v.w;
            }
        }
        if (half) sh[t & 127] = acc;
        __syncthreads();
        if (!half) {
            float4 o = sh[t];
            acc.x += o.x; acc.y += o.y; acc.z += o.z; acc.w += o.w;
            *(float4*)(part + b * 512 + c4) = acc;
        }
        return;
    }
    // ---- prep region ----
    u16* atpk = (u16*)(ws + WS_ATPK);
    u16* wfpk = (u16*)(ws + WS_WFPK);
    float* exA0 = ws + WS_EXA0;
    int id = (blockIdx.x - POOL_BLOCKS) * 256 + t;
    if (id < 32768) {                      // At[x][c] = sum_m wk_l[m,c]*wq_l[m,x]
        int h = id >> 8, c = id & 255;
        float s = 0.f;
        for (int m = 0; m < 128; ++m) s = fmaf(wk_l[m * 256 + c], wq_l[m * 128 + h], s);
        atpk[((h >> 3) * 272 + c) * 8 + (h & 7)] = f2bf(s);
    } else if (id < 65536) {               // Wf[c][h] = sum_m wv_l[m,c]*wo_l[h,m]
        int id2 = id - 32768;
        int c = id2 >> 7, h = id2 & 127;
        float s = 0.f;
        for (int m = 0; m < 128; ++m) s = fmaf(wv_l[m * 256 + c], wo_l[h * 128 + m], s);
        wfpk[((c >> 3) * 128 + h) * 8 + (c & 7)] = f2bf(s);
    } else if (id < 65792) {               // a0[c] = sum_m wk_l[m,c]*bq_l[m]
        int c = id - 65536;
        float s = 0.f;
        for (int m = 0; m < 128; ++m) s = fmaf(wk_l[m * 256 + c], bq_l[m], s);
        exA0[c] = s;
    } else if (id < 65920) {               // u[h] = sum_m bk_l[m]*wq_l[m,h] -> col 260
        int h = id - 65792;
        float s = 0.f;
        for (int m = 0; m < 128; ++m) s = fmaf(bk_l[m], wq_l[m * 128 + h], s);
        atpk[((h >> 3) * 272 + 260) * 8 + (h & 7)] = f2bf(s);
    } else if (id < 66048) {               // bf[h] = sum_m bv_l[m]*wo_l[h,m] + bo_l[h]
        int h = id - 65920;
        float s = bo_l[h];
        for (int m = 0; m < 128; ++m) s = fmaf(bv_l[m], wo_l[h * 128 + m], s);
        ws[WS_BF + h] = s;
    } else if (id == 66048) {              // c0 = bq_l . bk_l -> bias of col 260
        float s = 0.f;
        for (int m = 0; m < 128; ++m) s = fmaf(bq_l[m], bk_l[m], s);
        exA0[260] = s;
    } else if (id < 67457) {               // zero pad cols 261..271 of atpk
        int z = id - 66049;
        int col = 261 + (z >> 7), h = z & 127;
        atpk[((h >> 3) * 272 + col) * 8 + (h & 7)] = 0;
    } else if (id < PREP_ITEMS) {          // zero pad bias 261..271
        exA0[261 + (id - 67457)] = 0.f;
    }
}

// ---------- finish pooled mean; Mg(bf16 -> atpk cols 256-259), cg, Vo_g ----------
__global__ void k_finish(const float* __restrict__ wk_g, const float* __restrict__ wv_g,
                         const float* __restrict__ wq_g, const float* __restrict__ bk_g,
                         const float* __restrict__ bv_g, const float* __restrict__ bq_g,
                         const float* __restrict__ wo_g,
                         float* __restrict__ out_pool, float* __restrict__ ws) {
    __shared__ float pooled[512], kg[512], vg[512];
    int t = threadIdx.x; // 512 threads
    const float* part = ws + WS_PART;
    float s = 0.f;
    #pragma unroll 4
    for (int p = 0; p < POOL_BLOCKS; ++p) s += part[p * 512 + t];
    s *= (1.0f / 50000.0f);
    pooled[t]   = s;
    out_pool[t] = s;
    __syncthreads();
    int j = t >> 7, m = t & 127;
    float k = bk_g[m], v = bv_g[m];
    for (int h = 0; h < 128; ++h) {
        float p = pooled[j * 128 + h];
        k = fmaf(p, wk_g[m * 128 + h], k);
        v = fmaf(p, wv_g[m * 128 + h], v);
    }
    kg[t] = k; vg[t] = v;
    __syncthreads();
    {
        int h2 = t & 127;
        float s2 = 0.f, s3 = 0.f;
        for (int mm = 0; mm < 128; ++mm) {
            s2 = fmaf(wq_g[mm * 128 + h2], kg[j * 128 + mm], s2);
            s3 = fmaf(vg[j * 128 + mm], wo_g[h2 * 128 + mm], s3);
        }
        u16* atpk = (u16*)(ws + WS_ATPK);
        atpk[((h2 >> 3) * 272 + 256 + j) * 8 + (h2 & 7)] = f2bf(s2); // Mg col
        ws[WS_VOG + t] = s3;
    }
    if (t < 4) {
        float s4 = 0.f;
        for (int mm = 0; mm < 128; ++mm) s4 = fmaf(bq_g[mm], kg[t * 128 + mm], s4);
        (ws + WS_EXA0)[256 + t] = s4;                                // cg bias
    }
}

// ---------- main fused edge kernel: 32 edges/block, 4 waves ----------
template<bool GF16>
__global__ __launch_bounds__(256)
void k_main(const float* __restrict__ ea, const float* __restrict__ gf,
            const u16* __restrict__ gf16, const int* __restrict__ eidx,
            const float* __restrict__ bo_g, const float* __restrict__ ws,
            float* __restrict__ out) {
    __shared__ u16   lds_ea[32 * 128];      // bf16 ea, XOR-swizzled (<<3 in u16 units)
    __shared__ u16   lds_qk[32 * 256];      // bf16 qk, XOR-swizzled; reused as mixed
    __shared__ float lds_sc[32][8];         // per-edge: g0..g3 (cg folded), pb+c0
    __shared__ float lds_vog[512];
    __shared__ float lds_bog[128];

    const int t  = threadIdx.x;
    const int e0 = blockIdx.x * 32;
    const int w = t >> 6, lane = t & 63;
    const int colq = lane & 15, lhi = lane >> 4;

    // ---- stage ea -> bf16 LDS (swizzled) ----
    {
        int row = t >> 3, cc = (t & 7) * 16;
        const float4* src = (const float4*)(ea + (size_t)e0 * 128 + row * 128 + cc);
        float4 v0 = src[0], v1 = src[1], v2 = src[2], v3 = src[3];
        union { u16 h[16]; int4 q[2]; } tmp;
        tmp.h[0] = f2bf(v0.x); tmp.h[1] = f2bf(v0.y); tmp.h[2]  = f2bf(v0.z); tmp.h[3]  = f2bf(v0.w);
        tmp.h[4] = f2bf(v1.x); tmp.h[5] = f2bf(v1.y); tmp.h[6]  = f2bf(v1.z); tmp.h[7]  = f2bf(v1.w);
        tmp.h[8] = f2bf(v2.x); tmp.h[9] = f2bf(v2.y); tmp.h[10] = f2bf(v2.z); tmp.h[11] = f2bf(v2.w);
        tmp.h[12] = f2bf(v3.x); tmp.h[13] = f2bf(v3.y); tmp.h[14] = f2bf(v3.z); tmp.h[15] = f2bf(v3.w);
        int swz = (row & 7) << 3;
        *(int4*)&lds_ea[(row * 128 + cc) ^ swz]     = tmp.q[0];
        *(int4*)&lds_ea[(row * 128 + cc + 8) ^ swz] = tmp.q[1];
    }
    for (int i = t; i < 512; i += 256) lds_vog[i] = ws[WS_VOG + i];
    if (t < 128) lds_bog[t] = bo_g[t];
    __syncthreads();

    // ---- phase A (MFMA): qk_ext[32x272] = ea[32x128] @ Bext + biases ----
    {
        const short8* atpk = (const short8*)(ws + WS_ATPK);
        const float* exA0 = ws + WS_EXA0;
        f32x4 acc[2][4], accx[2];
        #pragma unroll
        for (int nt = 0; nt < 4; ++nt) {
            float a0v = exA0[w * 64 + nt * 16 + colq];
            acc[0][nt] = (f32x4){a0v, a0v, a0v, a0v};
            acc[1][nt] = (f32x4){a0v, a0v, a0v, a0v};
        }
        if (w == 3) {
            float av = exA0[256 + colq];
            accx[0] = (f32x4){av, av, av, av};
            accx[1] = (f32x4){av, av, av, av};
        }
        #pragma unroll
        for (int ks = 0; ks < 4; ++ks) {
            short8 afr[2];
            #pragma unroll
            for (int mt = 0; mt < 2; ++mt) {
                int row = mt * 16 + colq;
                afr[mt] = *(const short8*)&lds_ea[(row * 128 + ks * 32 + lhi * 8) ^ ((row & 7) << 3)];
            }
            int chunk = ks * 4 + lhi;
            #pragma unroll
            for (int nt = 0; nt < 4; ++nt) {
                short8 bfr = atpk[chunk * 272 + (w * 64 + nt * 16 + colq)];
                acc[0][nt] = __builtin_amdgcn_mfma_f32_16x16x32_bf16(afr[0], bfr, acc[0][nt], 0, 0, 0);
                acc[1][nt] = __builtin_amdgcn_mfma_f32_16x16x32_bf16(afr[1], bfr, acc[1][nt], 0, 0, 0);
            }
            if (w == 3) {
                short8 bx = atpk[chunk * 272 + 256 + colq];
                accx[0] = __builtin_amdgcn_mfma_f32_16x16x32_bf16(afr[0], bx, accx[0], 0, 0, 0);
                accx[1] = __builtin_amdgcn_mfma_f32_16x16x32_bf16(afr[1], bx, accx[1], 0, 0, 0);
            }
        }
        #pragma unroll
        for (int mt = 0; mt < 2; ++mt)
            #pragma unroll
            for (int nt = 0; nt < 4; ++nt) {
                int c = w * 64 + nt * 16 + colq;
                #pragma unroll
                for (int j = 0; j < 4; ++j) {
                    int row = mt * 16 + lhi * 4 + j;
                    lds_qk[(row * 256 + c) ^ ((row & 7) << 3)] = f2bf(acc[mt][nt][j]);
                }
            }
        if (w == 3 && colq < 5) {
            #pragma unroll
            for (int mt = 0; mt < 2; ++mt)
                #pragma unroll
                for (int j = 0; j < 4; ++j)
                    lds_sc[mt * 16 + lhi * 4 + j][colq] = accx[mt][j];
        }
    }
    __syncthreads();

    // ---- middle: per-wave 8 edges ----
    {
        const int eBase = w * 8;
        int i0s[8], i1s[8];
        #pragma unroll
        for (int ee = 0; ee < 8; ++ee) {
            int eG = e0 + eBase + ee;
            i0s[ee] = eidx[eG]; i1s[ee] = eidx[E_EDGES + eG];
        }
        const float2 bog2 = *(const float2*)&lds_bog[2 * lane];
        const float2 vg0  = *(const float2*)&lds_vog[2 * lane];
        const float2 vg1  = *(const float2*)&lds_vog[128 + 2 * lane];
        const float2 vg2  = *(const float2*)&lds_vog[256 + 2 * lane];
        const float2 vg3  = *(const float2*)&lds_vog[384 + 2 * lane];

        u32 Sr[4], Dr[4];
        float2 Sf[4], Df[4];
        if (GF16) {
            const u16* ps = gf16 + (size_t)i0s[0] * 512;
            const u16* pd = gf16 + (size_t)i1s[0] * 512;
            #pragma unroll
            for (int s = 0; s < 4; ++s) {
                Sr[s] = *(const u32*)(ps + s * 128 + 2 * lane);
                Dr[s] = *(const u32*)(pd + s * 128 + 2 * lane);
            }
        } else {
            const float* ps = gf + (size_t)i0s[0] * 512;
            const float* pd = gf + (size_t)i1s[0] * 512;
            #pragma unroll
            for (int s = 0; s < 4; ++s) {
                Sf[s] = *(const float2*)(ps + s * 128 + 2 * lane);
                Df[s] = *(const float2*)(pd + s * 128 + 2 * lane);
            }
        }
        #pragma unroll
        for (int ee = 0; ee < 8; ++ee) {
            int eL = eBase + ee, eG = e0 + eL;
            float2 Sc[4], Dc[4];
            if (GF16) {
                #pragma unroll
                for (int s = 0; s < 4; ++s) {
                    Sc[s].x = blo(Sr[s]); Sc[s].y = bhi(Sr[s]);
                    Dc[s].x = blo(Dr[s]); Dc[s].y = bhi(Dr[s]);
                }
            } else {
                #pragma unroll
                for (int s = 0; s < 4; ++s) { Sc[s] = Sf[s]; Dc[s] = Df[s]; }
            }
            if (ee < 7) {   // prefetch next edge's gather
                if (GF16) {
                    const u16* ps = gf16 + (size_t)i0s[ee + 1] * 512;
                    const u16* pd = gf16 + (size_t)i1s[ee + 1] * 512;
                    #pragma unroll
                    for (int s = 0; s < 4; ++s) {
                        Sr[s] = *(const u32*)(ps + s * 128 + 2 * lane);
                        Dr[s] = *(const u32*)(pd + s * 128 + 2 * lane);
                    }
                } else {
                    const float* ps = gf + (size_t)i0s[ee + 1] * 512;
                    const float* pd = gf + (size_t)i1s[ee + 1] * 512;
                    #pragma unroll
                    for (int s = 0; s < 4; ++s) {
                        Sf[s] = *(const float2*)(ps + s * 128 + 2 * lane);
                        Df[s] = *(const float2*)(pd + s * 128 + 2 * lane);
                    }
                }
            }
            const int swzh = (eL & 7) << 3;
            u32 qsr = *(const u32*)&lds_qk[(eL * 256 + 2 * lane) ^ swzh];
            u32 qdr = *(const u32*)&lds_qk[(eL * 256 + 128 + 2 * lane) ^ swzh];
            float qsx = blo(qsr), qsy = bhi(qsr), qdx = blo(qdr), qdy = bhi(qdr);

            float p0 = Sc[0].x * qsx + Sc[0].y * qsy + Dc[0].x * qdx + Dc[0].y * qdy;
            float p1 = Sc[1].x * qsx + Sc[1].y * qsy + Dc[1].x * qdx + Dc[1].y * qdy;
            float p2 = Sc[2].x * qsx + Sc[2].y * qsy + Dc[2].x * qdx + Dc[2].y * qdy;
            float p3 = Sc[3].x * qsx + Sc[3].y * qsy + Dc[3].x * qdx + Dc[3].y * qdy;
            #pragma unroll
            for (int off = 32; off; off >>= 1) {
                p0 += __shfl_xor(p0, off, 64); p1 += __shfl_xor(p1, off, 64);
                p2 += __shfl_xor(p2, off, 64); p3 += __shfl_xor(p3, off, 64);
            }
            float pbc0 = lds_sc[eL][4];
            float t0 = (p0 + pbc0) * SCALE, t1 = (p1 + pbc0) * SCALE;
            float t2 = (p2 + pbc0) * SCALE, t3 = (p3 + pbc0) * SCALE;
            float mx = fmaxf(fmaxf(t0, t1), fmaxf(t2, t3));
            float x0 = __expf(t0 - mx), x1 = __expf(t1 - mx);
            float x2 = __expf(t2 - mx), x3 = __expf(t3 - mx);
            float inv = 1.0f / (x0 + x1 + x2 + x3);
            float a0s = x0 * inv, a1s = x1 * inv, a2s = x2 * inv, a3s = x3 * inv;

            float s0 = lds_sc[eL][0] * SCALE, s1 = lds_sc[eL][1] * SCALE;
            float s2 = lds_sc[eL][2] * SCALE, s3 = lds_sc[eL][3] * SCALE;
            float mg = fmaxf(fmaxf(s0, s1), fmaxf(s2, s3));
            float y0 = __expf(s0 - mg), y1 = __expf(s1 - mg);
            float y2 = __expf(s2 - mg), y3 = __expf(s3 - mg);
            float invg = 1.0f / (y0 + y1 + y2 + y3);
            float b0 = y0 * invg, b1 = y1 * invg, b2 = y2 * invg, b3 = y3 * invg;

            size_t ro = (size_t)eG * 384;
            if (lane < 4)
                out[OUT_GAW + (size_t)eG * 4 + lane] =
                    (lane == 0) ? b0 : (lane == 1) ? b1 : (lane == 2) ? b2 : b3;

            float2 go;
            go.x = bog2.x + b0 * vg0.x + b1 * vg1.x + b2 * vg2.x + b3 * vg3.x;
            go.y = bog2.y + b0 * vg0.y + b1 * vg1.y + b2 * vg2.y + b3 * vg3.y;
            *(float2*)(out + ro + 256 + 2 * lane) = go;

            float2 pth = *(const float2*)(ea + (size_t)eG * 128 + 2 * lane);  // exact passthrough
            *(float2*)(out + ro + 2 * lane) = pth;

            // mixed -> bf16 into qk buffer: channels contiguous [0,256) per row
            float msx = a0s * Sc[0].x + a1s * Sc[1].x + a2s * Sc[2].x + a3s * Sc[3].x;
            float msy = a0s * Sc[0].y + a1s * Sc[1].y + a2s * Sc[2].y + a3s * Sc[3].y;
            float mdx = a0s * Dc[0].x + a1s * Dc[1].x + a2s * Dc[2].x + a3s * Dc[3].x;
            float mdy = a0s * Dc[0].y + a1s * Dc[1].y + a2s * Dc[2].y + a3s * Dc[3].y;
            u32 pks = (u32)f2bf(msx) | ((u32)f2bf(msy) << 16);
            u32 pkd = (u32)f2bf(mdx) | ((u32)f2bf(mdy) << 16);
            *(u32*)&lds_qk[(eL * 256 + 2 * lane) ^ swzh]       = pks;
            *(u32*)&lds_qk[(eL * 256 + 128 + 2 * lane) ^ swzh] = pkd;
        }
    }
    __syncthreads();

    // ---- phase B (MFMA): local_out[32x128] = mixed[32x256] @ Wf[256x128] + bf ----
    {
        const short8* wfpk = (const short8*)(ws + WS_WFPK);
        f32x4 acc[2][2];
        #pragma unroll
        for (int nt = 0; nt < 2; ++nt) {
            float bfv = ws[WS_BF + w * 32 + nt * 16 + colq];
            acc[0][nt] = (f32x4){bfv, bfv, bfv, bfv};
            acc[1][nt] = (f32x4){bfv, bfv, bfv, bfv};
        }
        #pragma unroll
        for (int ks = 0; ks < 8; ++ks) {
            short8 afr[2];
            #pragma unroll
            for (int mt = 0; mt < 2; ++mt) {
                int row = mt * 16 + colq;
                afr[mt] = *(const short8*)&lds_qk[(row * 256 + ks * 32 + lhi * 8) ^ ((row & 7) << 3)];
            }
            int chunk = ks * 4 + lhi;
            #pragma unroll
            for (int nt = 0; nt < 2; ++nt) {
                short8 bfr = wfpk[chunk * 128 + (w * 32 + nt * 16 + colq)];
                acc[0][nt] = __builtin_amdgcn_mfma_f32_16x16x32_bf16(afr[0], bfr, acc[0][nt], 0, 0, 0);
                acc[1][nt] = __builtin_amdgcn_mfma_f32_16x16x32_bf16(afr[1], bfr, acc[1][nt], 0, 0, 0);
            }
        }
        #pragma unroll
        for (int mt = 0; mt < 2; ++mt)
            #pragma unroll
            for (int nt = 0; nt < 2; ++nt) {
                int c = w * 32 + nt * 16 + colq;
                #pragma unroll
                for (int j = 0; j < 4; ++j) {
                    int row = mt * 16 + lhi * 4 + j;
                    out[(size_t)(e0 + row) * 384 + 128 + c] = acc[mt][nt][j];
                }
            }
    }
}

extern "C" void kernel_launch(void* const* d_in, const int* in_sizes, int n_in,
                              void* d_out, int out_size, void* d_ws, size_t ws_size,
                              hipStream_t stream) {
    const float* edge_attr = (const float*)d_in[0];
    const float* gf        = (const float*)d_in[1];
    const int*   eidx      = (const int*)d_in[2];
    const float* wq_l = (const float*)d_in[3];
    const float* wk_l = (const float*)d_in[4];
    const float* wv_l = (const float*)d_in[5];
    const float* bq_l = (const float*)d_in[6];
    const float* bk_l = (const float*)d_in[7];
    const float* bv_l = (const float*)d_in[8];
    const float* wo_l = (const float*)d_in[9];
    const float* bo_l = (const float*)d_in[10];
    const float* wq_g = (const float*)d_in[11];
    const float* wk_g = (const float*)d_in[12];
    const float* wv_g = (const float*)d_in[13];
    const float* bq_g = (const float*)d_in[14];
    const float* bk_g = (const float*)d_in[15];
    const float* bv_g = (const float*)d_in[16];
    const float* wo_g = (const float*)d_in[17];
    const float* bo_g = (const float*)d_in[18];

    float* out = (float*)d_out;
    float* ws  = (float*)d_ws;

    const bool useGF16 = ws_size >= (size_t)WS_FLOATS_GF16 * 4;
    u16* gf16 = useGF16 ? (u16*)(ws + WS_GF16) : nullptr;

    k_pre<<<POOL_BLOCKS + PREP_BLOCKS, 256, 0, stream>>>(
        gf, wq_l, wk_l, wv_l, bq_l, bk_l, bv_l, wo_l, bo_l, gf16, ws);
    k_finish<<<1, 512, 0, stream>>>(wk_g, wv_g, wq_g, bk_g, bv_g, bq_g, wo_g,
                                    out + OUT_POOL, ws);
    if (useGF16)
        k_main<true><<<E_EDGES / 32, 256, 0, stream>>>(edge_attr, gf, gf16, eidx, bo_g, ws, out);
    else
        k_main<false><<<E_EDGES / 32, 256, 0, stream>>>(edge_attr, gf, nullptr, eidx, bo_g, ws, out);
}